// Round 3
// baseline (13532.639 us; speedup 1.0000x reference)
//
#include <hip/hip_runtime.h>
#include <math.h>

#define BSZ 512
#define SEQ 128
#define FF  136
#define HH  128

// ---------------- transpose (384x128 -> 128x384) ----------------
__global__ __launch_bounds__(256) void k_transpose384(const float* __restrict__ A,
                                                      float* __restrict__ At) {
    int i = blockIdx.x * 256 + threadIdx.x;          // over 384*128
    if (i < 384 * 128) {
        int r = i >> 7, c = i & 127;
        At[c * 384 + r] = A[i];
    }
}

// ---------------- fused doc FNN + V + GI precompute ----------------
__global__ __launch_bounds__(256) void k_docvgi(
    const float* __restrict__ br,
    const float* __restrict__ fW1, const float* __restrict__ fb1,
    const float* __restrict__ fW2, const float* __restrict__ fb2,
    const float* __restrict__ comW1,
    const float* __restrict__ WihT, const float* __restrict__ bih,
    float* __restrict__ V, float* __restrict__ GI)
{
    __shared__ float xs[32][FF];
    __shared__ float hs[32][HH];
    __shared__ float ds[32][HH];
    int row0 = blockIdx.x * 32;
    int t = threadIdx.x;
    const float* src = br + (size_t)row0 * FF;
    for (int i = t; i < 32 * FF; i += 256) xs[i / FF][i % FF] = src[i];
    __syncthreads();
    int j = t & 127, rg = t >> 7;
    float acc[16];
#pragma unroll
    for (int r = 0; r < 16; r++) acc[r] = 0.f;
    for (int k = 0; k < FF; k++) {
        float w = fW1[k * HH + j];
#pragma unroll
        for (int r = 0; r < 16; r++) acc[r] += xs[rg + 2 * r][k] * w;
    }
    {
        float bb = fb1[j];
#pragma unroll
        for (int r = 0; r < 16; r++) hs[rg + 2 * r][j] = fmaxf(acc[r] + bb, 0.f);
    }
    __syncthreads();
#pragma unroll
    for (int r = 0; r < 16; r++) acc[r] = 0.f;
    for (int k = 0; k < HH; k++) {
        float w = fW2[k * HH + j];
#pragma unroll
        for (int r = 0; r < 16; r++) acc[r] += hs[rg + 2 * r][k] * w;
    }
    {
        float bb = fb2[j];
#pragma unroll
        for (int r = 0; r < 16; r++)
            ds[rg + 2 * r][j] = 1.f / (1.f + expf(-(acc[r] + bb)));
    }
    __syncthreads();
#pragma unroll
    for (int r = 0; r < 16; r++) acc[r] = 0.f;
    for (int k = 0; k < HH; k++) {
        float w = comW1[k * HH + j];
#pragma unroll
        for (int r = 0; r < 16; r++) acc[r] += ds[rg + 2 * r][k] * w;
    }
#pragma unroll
    for (int r = 0; r < 16; r++) V[(size_t)(row0 + rg + 2 * r) * HH + j] = acc[r];
    for (int p = 0; p < 3; p++) {
        int jj = p * HH + j;
#pragma unroll
        for (int r = 0; r < 16; r++) acc[r] = 0.f;
        for (int k = 0; k < HH; k++) {
            float w = WihT[k * 384 + jj];
#pragma unroll
            for (int r = 0; r < 16; r++) acc[r] += ds[rg + 2 * r][k] * w;
        }
        float bb = bih[jj];
#pragma unroll
        for (int r = 0; r < 16; r++)
            GI[(size_t)(row0 + rg + 2 * r) * 384 + jj] = acc[r] + bb;
    }
}

// ---------------- scan: 1 batch elem per block, 512 threads, GRU overlapped ----------------
__global__ __launch_bounds__(512, 4) void k_scan3(
    const float* __restrict__ br,
    const float* __restrict__ cntW1, const float* __restrict__ cntb1,
    const float* __restrict__ cntW2, const float* __restrict__ cntb2,
    const float* __restrict__ comW1, const float* __restrict__ comb1,
    const float* __restrict__ comW2,
    const float* __restrict__ WhhT, const float* __restrict__ gbhh,
    const float* __restrict__ V, const float* __restrict__ GI,
    float* __restrict__ out)
{
    __shared__ float  Vl[SEQ][HH + 1];      // 66 KB, pad -> 2-way (free) conflicts
    __shared__ double svS[HH], mxvS[HH];    // incremental cnt-net preactivation parts
    __shared__ float  a1S[HH], crS[HH], uS[HH], hS[HH], c2S[HH];
    __shared__ float  ghS[256];             // gh for r,z gates (full-k)
    __shared__ float  ghp2[2][HH];          // gh partials for n gate
    __shared__ float  ppB[2][HH], ppC[4][HH], ppD[4][HH];
    __shared__ float  svp[HH];
    __shared__ float  mxS[FF], chgD[FF];
    __shared__ int    mxiS[FF], chgF[FF], maskS[SEQ];
    __shared__ int    selS, chgN;

    const int b = blockIdx.x;
    const int t = threadIdx.x;
    const float* brB = br + (size_t)b * SEQ * FF;
    const float* GIb = GI + (size_t)b * SEQ * 384;

    // ---- init ----
    {
        const float* Vb = V + (size_t)b * SEQ * HH;
        for (int idx = t; idx < SEQ * HH; idx += 512)
            Vl[idx >> 7][idx & 127] = Vb[idx];
    }
    if (t < HH)  { hS[t] = 0.f; c2S[t] = comW2[t]; }
    if (t < SEQ) maskS[t] = 1;
    if (t < FF) {
        float cs = 0.f; float mx = -__builtin_huge_valf(); int mi = 0;
        const float* bp = brB + t;
        for (int s = 0; s < SEQ; s++) {
            float v = bp[s * FF];
            cs += v;
            if (v > mx) { mx = v; mi = s; }
        }
        mxS[t] = mx; mxiS[t] = mi; chgD[t] = cs;
    }
    if (t == 256) chgN = 0;
    __syncthreads();
    if (t < HH) {
        double am = 0.0, as = 0.0;
        for (int f = 0; f < FF; f++) {
            am += (double)mxS[f]  * (double)cntW1[f * HH + t];
            as += (double)chgD[f] * (double)cntW1[(FF + f) * HH + t];
        }
        mxvS[t] = am; svS[t] = as;
        a1S[t] = fmaxf((float)(am + as / 128.0) + cntb1[t], 0.f);
    }
    __syncthreads();

    for (int i = 0; i < SEQ; i++) {
        // ---- P1: B = a1 @ cntW2 (k-split2)  ||  G1: gh[r,z] = h @ WhhT[:, 0:256] ----
        if (t < 256) {
            int kh = t >> 7, j = t & 127;
            const float* W = cntW2 + (size_t)(kh * 64) * HH + j;
            const float* a = a1S + kh * 64;
            float acc = 0.f;
            for (int m = 0; m < 64; m++) acc += a[m] * W[m * HH];
            ppB[kh][j] = acc;
        } else {
            int jj = t - 256;
            const float* W = WhhT + jj;
            float acc = 0.f;
            for (int k = 0; k < 128; k++) acc += hS[k] * W[k * 384];
            ghS[jj] = acc;
        }
        __syncthreads();

        // ---- P2: cr = sigmoid(B + b2)  ||  G2: gh[n] partials (k-split2) ----
        if (t < HH) {
            crS[t] = 1.f / (1.f + expf(-(ppB[0][t] + ppB[1][t] + cntb2[t])));
        } else if (t == HH) {
            chgN = 0;                         // reset before this step's P8 atomics
        } else if (t >= 256) {
            int r = t - 256, kh = r >> 7, j = r & 127;
            const float* W = WhhT + 256 + j;
            const float* h = hS + kh * 64;
            float acc = 0.f;
            for (int m = 0; m < 64; m++) acc += h[m] * W[(kh * 64 + m) * 384];
            ghp2[kh][j] = acc;
        }
        __syncthreads();

        // ---- P3: C partials: [cr|h] @ comW1[128:384] (k-split4) ----
        {
            int q = t >> 7, j = t & 127;
            const float* W = comW1 + (size_t)(HH + q * 64) * HH + j;
            const float* s0 = (q < 2) ? (crS + q * 64) : (hS + (q - 2) * 64);
            float acc = 0.f;
            for (int m = 0; m < 64; m++) acc += s0[m] * W[m * HH];
            ppC[q][j] = acc;
        }
        __syncthreads();

        // ---- P4: u reduce ----
        if (t < HH) uS[t] = ppC[0][t] + ppC[1][t] + ppC[2][t] + ppC[3][t] + comb1[t];
        __syncthreads();

        // ---- P5: D partials: scores (k-split4) ----
        {
            int q = t >> 7, s = t & 127, k0 = q * 32;
            float acc = 0.f;
            for (int m = 0; m < 32; m++) {
                int k = k0 + m;
                acc += c2S[k] * fmaxf(Vl[s][k] + uS[k], 0.f);
            }
            ppD[q][s] = acc;
        }
        __syncthreads();

        // ---- P6: score reduce ----
        if (t < SEQ) ppD[0][t] = ppD[0][t] + ppD[1][t] + ppD[2][t] + ppD[3][t];
        __syncthreads();

        // ---- P7: masked argmax (wave 0), first-index tie break ----
        if (t < 64) {
            float v1 = maskS[t]      ? ppD[0][t]      : -__builtin_huge_valf();
            float v2 = maskS[t + 64] ? ppD[0][t + 64] : -__builtin_huge_valf();
            float v; int idx;
            if (v2 > v1) { v = v2; idx = t + 64; } else { v = v1; idx = t; }
            for (int off = 32; off >= 1; off >>= 1) {
                float ov = __shfl_down(v, off);
                int   oi = __shfl_down(idx, off);
                if (ov > v || (ov == v && oi < idx)) { v = ov; idx = oi; }
            }
            if (t == 0) {
                selS = idx;
                maskS[idx] = 0;
                out[(size_t)b * SEQ + idx] = powf(0.9f, (float)i);
            }
        }
        __syncthreads();
        int sel = selS;

        // ---- P8: max maintenance || sel-row @ W1b || GRU epilogue ----
        if (i < SEQ - 1) {
            if (t < FF) {
                if (sel == mxiS[t]) {
                    float om = mxS[t];
                    float mx = -__builtin_huge_valf(); int mi = 0;
                    const float* bp = brB + t;
                    for (int s = 0; s < SEQ; s++) {
                        if (maskS[s]) { float v = bp[s * FF]; if (v > mx) { mx = v; mi = s; } }
                    }
                    mxS[t] = mx; mxiS[t] = mi;
                    int e = atomicAdd(&chgN, 1);
                    chgF[e] = t; chgD[e] = mx - om;
                }
            } else if (t >= 256 && t < 384) {
                int j = t - 256;
                const float* brow = brB + (size_t)sel * FF;
                const float* W = cntW1 + (size_t)FF * HH + j;
                float acc = 0.f;
                for (int k = 0; k < FF; k++) acc += brow[k] * W[k * HH];
                svp[j] = acc;
            } else if (t >= 384) {
                int j = t - 384;
                const float* gir = GIb + (size_t)sel * 384;
                float ghr = ghS[j]           + gbhh[j];
                float ghz = ghS[HH + j]      + gbhh[HH + j];
                float ghn = ghp2[0][j] + ghp2[1][j] + gbhh[2 * HH + j];
                float rr = 1.f / (1.f + expf(-(gir[j] + ghr)));
                float zz = 1.f / (1.f + expf(-(gir[HH + j] + ghz)));
                float nn = tanhf(gir[2 * HH + j] + rr * ghn);
                hS[j] = (1.f - zz) * nn + zz * hS[j];   // only thread j touches hS[j]
            }
        }
        __syncthreads();

        // ---- P9: apply incremental updates, compute next a1 ----
        if (i < SEQ - 1 && t < HH) {
            double acc = mxvS[t];
            int n = chgN;
            for (int e = 0; e < n; e++)
                acc += (double)chgD[e] * (double)cntW1[chgF[e] * HH + t];
            mxvS[t] = acc;
            double sv = svS[t] - (double)svp[t];
            svS[t] = sv;
            a1S[t] = fmaxf((float)(acc + sv / (double)(SEQ - 1 - i)) + cntb1[t], 0.f);
        }
        __syncthreads();
    }
}

extern "C" void kernel_launch(void* const* d_in, const int* in_sizes, int n_in,
                              void* d_out, int out_size, void* d_ws, size_t ws_size,
                              hipStream_t stream) {
    (void)in_sizes; (void)n_in; (void)out_size; (void)ws_size;
    const float* br    = (const float*)d_in[0];
    const float* fnnW1 = (const float*)d_in[2];
    const float* fnnb1 = (const float*)d_in[3];
    const float* fnnW2 = (const float*)d_in[4];
    const float* fnnb2 = (const float*)d_in[5];
    const float* cntW1 = (const float*)d_in[6];
    const float* cntb1 = (const float*)d_in[7];
    const float* cntW2 = (const float*)d_in[8];
    const float* cntb2 = (const float*)d_in[9];
    const float* comW1 = (const float*)d_in[10];
    const float* comb1 = (const float*)d_in[11];
    const float* comW2 = (const float*)d_in[12];
    const float* Wih   = (const float*)d_in[14];
    const float* Whh   = (const float*)d_in[15];
    const float* bih   = (const float*)d_in[16];
    const float* bhh   = (const float*)d_in[17];

    float* ws   = (float*)d_ws;
    float* V    = ws;                         // 512*128*128      =  8,388,608 f
    float* GI   = ws + 8388608;               // 512*128*384      = 25,165,824 f
    float* WihT = ws + 8388608 + 25165824;    // 128*384          =     49,152 f
    float* WhhT = WihT + 49152;               // 128*384          =     49,152 f

    hipLaunchKernelGGL(k_transpose384, dim3(192), dim3(256), 0, stream, Wih, WihT);
    hipLaunchKernelGGL(k_transpose384, dim3(192), dim3(256), 0, stream, Whh, WhhT);
    hipLaunchKernelGGL(k_docvgi, dim3(2048), dim3(256), 0, stream,
                       br, fnnW1, fnnb1, fnnW2, fnnb2, comW1, WihT, bih, V, GI);
    hipLaunchKernelGGL(k_scan3, dim3(BSZ), dim3(512), 0, stream,
                       br, cntW1, cntb1, cntW2, cntb2, comW1, comb1, comW2,
                       WhhT, bhh, V, GI, (float*)d_out);
}

// Round 4
// 9824.296 us; speedup vs baseline: 1.3775x; 1.3775x over previous
//
#include <hip/hip_runtime.h>
#include <math.h>

#define BSZ 512
#define SEQ 128
#define FF  136
#define HH  128

// ---------------- transpose (384x128 -> 128x384) ----------------
__global__ __launch_bounds__(256) void k_transpose384(const float* __restrict__ A,
                                                      float* __restrict__ At) {
    int i = blockIdx.x * 256 + threadIdx.x;          // over 384*128
    if (i < 384 * 128) {
        int r = i >> 7, c = i & 127;
        At[c * 384 + r] = A[i];
    }
}

// ---------------- fused doc FNN + V + GI + SV precompute ----------------
__global__ __launch_bounds__(256) void k_docvgi(
    const float* __restrict__ br,
    const float* __restrict__ fW1, const float* __restrict__ fb1,
    const float* __restrict__ fW2, const float* __restrict__ fb2,
    const float* __restrict__ comW1,
    const float* __restrict__ WihT, const float* __restrict__ bih,
    const float* __restrict__ cntW1,
    float* __restrict__ V, float* __restrict__ GI, float* __restrict__ SV)
{
    __shared__ float xs[32][FF];
    __shared__ float hs[32][HH];
    __shared__ float ds[32][HH];
    int row0 = blockIdx.x * 32;
    int t = threadIdx.x;
    const float* src = br + (size_t)row0 * FF;
    for (int i = t; i < 32 * FF; i += 256) xs[i / FF][i % FF] = src[i];
    __syncthreads();
    int j = t & 127, rg = t >> 7;
    float acc[16];
    // layer 1
#pragma unroll
    for (int r = 0; r < 16; r++) acc[r] = 0.f;
    for (int k = 0; k < FF; k++) {
        float w = fW1[k * HH + j];
#pragma unroll
        for (int r = 0; r < 16; r++) acc[r] += xs[rg + 2 * r][k] * w;
    }
    {
        float bb = fb1[j];
#pragma unroll
        for (int r = 0; r < 16; r++) hs[rg + 2 * r][j] = fmaxf(acc[r] + bb, 0.f);
    }
    __syncthreads();
    // layer 2 -> doc
#pragma unroll
    for (int r = 0; r < 16; r++) acc[r] = 0.f;
    for (int k = 0; k < HH; k++) {
        float w = fW2[k * HH + j];
#pragma unroll
        for (int r = 0; r < 16; r++) acc[r] += hs[rg + 2 * r][k] * w;
    }
    {
        float bb = fb2[j];
#pragma unroll
        for (int r = 0; r < 16; r++)
            ds[rg + 2 * r][j] = 1.f / (1.f + expf(-(acc[r] + bb)));
    }
    __syncthreads();
    // V = doc @ comW1[0:128,:]
#pragma unroll
    for (int r = 0; r < 16; r++) acc[r] = 0.f;
    for (int k = 0; k < HH; k++) {
        float w = comW1[k * HH + j];
#pragma unroll
        for (int r = 0; r < 16; r++) acc[r] += ds[rg + 2 * r][k] * w;
    }
#pragma unroll
    for (int r = 0; r < 16; r++) V[(size_t)(row0 + rg + 2 * r) * HH + j] = acc[r];
    // GI = doc @ WihT + bih
    for (int p = 0; p < 3; p++) {
        int jj = p * HH + j;
#pragma unroll
        for (int r = 0; r < 16; r++) acc[r] = 0.f;
        for (int k = 0; k < HH; k++) {
            float w = WihT[k * 384 + jj];
#pragma unroll
            for (int r = 0; r < 16; r++) acc[r] += ds[rg + 2 * r][k] * w;
        }
        float bb = bih[jj];
#pragma unroll
        for (int r = 0; r < 16; r++)
            GI[(size_t)(row0 + rg + 2 * r) * 384 + jj] = acc[r] + bb;
    }
    // SV = br @ cntW1[FF:2FF,:]   (per-row mean-path contribution)
#pragma unroll
    for (int r = 0; r < 16; r++) acc[r] = 0.f;
    for (int k = 0; k < FF; k++) {
        float w = cntW1[(FF + k) * HH + j];
#pragma unroll
        for (int r = 0; r < 16; r++) acc[r] += xs[rg + 2 * r][k] * w;
    }
#pragma unroll
    for (int r = 0; r < 16; r++) SV[(size_t)(row0 + rg + 2 * r) * HH + j] = acc[r];
}

// ---------------- scan: 1 elem/block, 256 threads (round-1 shape, phase A removed) ----------------
__global__ __launch_bounds__(256) void k_scan4(
    const float* __restrict__ br,
    const float* __restrict__ cntW1, const float* __restrict__ cntb1,
    const float* __restrict__ cntW2, const float* __restrict__ cntb2,
    const float* __restrict__ comW1, const float* __restrict__ comb1,
    const float* __restrict__ comW2,
    const float* __restrict__ WhhT, const float* __restrict__ gbhh,
    const float* __restrict__ V, const float* __restrict__ GI,
    const float* __restrict__ SV,
    float* __restrict__ out)
{
    __shared__ float  Vl[SEQ][HH + 1];      // 66 KB, padded
    __shared__ double svS[HH], mxvS[HH];
    __shared__ float  a1S[HH], crS[HH], uS[HH], hS[HH], c2S[HH];
    __shared__ float  ppB[2][HH], ppC[2][HH], ppD[2][HH], ppG[6][HH];
    __shared__ float  rowS[512];            // [0:384) GI row, [384:512) SV row
    __shared__ float  mxS[FF], chgDl[FF];
    __shared__ int    mxiS[FF], chgF[FF], maskS[SEQ];
    __shared__ int    selS, chgN;

    const int b = blockIdx.x;
    const int t = threadIdx.x;
    const float* brB = br + (size_t)b * SEQ * FF;
    const float* GIb = GI + (size_t)b * SEQ * 384;
    const float* SVb = SV + (size_t)b * SEQ * HH;

    // ---- init ----
    {
        const float* Vb = V + (size_t)b * SEQ * HH;
        for (int idx = t; idx < SEQ * HH; idx += 256)
            Vl[idx >> 7][idx & 127] = Vb[idx];
    }
    if (t < HH)  { hS[t] = 0.f; c2S[t] = comW2[t]; }
    if (t < SEQ) maskS[t] = 1;
    if (t < FF) {
        float cs = 0.f; float mx = -__builtin_huge_valf(); int mi = 0;
        const float* bp = brB + t;
        for (int s = 0; s < SEQ; s++) {
            float v = bp[s * FF];
            cs += v;
            if (v > mx) { mx = v; mi = s; }
        }
        mxS[t] = mx; mxiS[t] = mi; chgDl[t] = cs;   // chgDl temporarily holds colsum
    }
    __syncthreads();
    if (t < HH) {
        double am = 0.0, as = 0.0;
        for (int f = 0; f < FF; f++) {
            am += (double)mxS[f]   * (double)cntW1[f * HH + t];
            as += (double)chgDl[f] * (double)cntW1[(FF + f) * HH + t];
        }
        mxvS[t] = am; svS[t] = as;
        a1S[t] = fmaxf((float)(am + as / 128.0) + cntb1[t], 0.f);
    }
    __syncthreads();

    for (int i = 0; i < SEQ; i++) {
        const int kh = t >> 7, j = t & 127;

        // ---- B: ppB = a1 @ cntW2 (k-split2) ----
        {
            const float* W = cntW2 + (size_t)(kh * 64) * HH + j;
            const float* a = a1S + kh * 64;
            float acc = 0.f;
            for (int m = 0; m < 64; m++) acc += a[m] * W[m * HH];
            ppB[kh][j] = acc;
        }
        __syncthreads();

        // ---- cr = sigmoid(.) ; reset chg counter ----
        if (t < HH) crS[t] = 1.f / (1.f + expf(-(ppB[0][t] + ppB[1][t] + cntb2[t])));
        else if (t == HH) chgN = 0;
        __syncthreads();

        // ---- C: u-halves: cr @ comW1[128:256] (kh=0) | h @ comW1[256:384] (kh=1) ----
        {
            const float* W = comW1 + (size_t)(HH + kh * HH) * HH + j;
            const float* s0 = kh ? hS : crS;
            float acc = 0.f;
            for (int m = 0; m < 128; m++) acc += s0[m] * W[m * HH];
            ppC[kh][j] = acc;
        }
        __syncthreads();
        if (t < HH) uS[t] = ppC[0][t] + ppC[1][t] + comb1[t];
        __syncthreads();

        // ---- D: score partials (k-split2, LDS) ----
        {
            float acc = 0.f;
            const int k0 = kh * 64;
            for (int m = 0; m < 64; m++) {
                int k = k0 + m;
                acc += c2S[k] * fmaxf(Vl[j][k] + uS[k], 0.f);
            }
            ppD[kh][j] = acc;
        }
        __syncthreads();

        // ---- argmax (wave 0 reduces partials directly) ----
        if (t < 64) {
            float s1 = ppD[0][t] + ppD[1][t];
            float s2 = ppD[0][t + 64] + ppD[1][t + 64];
            float v1 = maskS[t]      ? s1 : -__builtin_huge_valf();
            float v2 = maskS[t + 64] ? s2 : -__builtin_huge_valf();
            float v; int idx;
            if (v2 > v1) { v = v2; idx = t + 64; } else { v = v1; idx = t; }
            for (int off = 32; off >= 1; off >>= 1) {
                float ov = __shfl_down(v, off);
                int   oi = __shfl_down(idx, off);
                if (ov > v || (ov == v && oi < idx)) { v = ov; idx = oi; }
            }
            if (t == 0) {
                selS = idx;
                maskS[idx] = 0;
                out[(size_t)b * SEQ + idx] = powf(0.9f, (float)i);
            }
        }
        __syncthreads();
        const int sel = selS;

        // ---- P8: detect stale maxes (t<136) | load GI+SV rows (t>=136) ----
        if (i < SEQ - 1) {
            if (t < FF) {
                if (sel == mxiS[t]) {
                    int e = atomicAdd(&chgN, 1);
                    chgF[e] = t;
                }
            } else {
                const float* gir = GIb + (size_t)sel * 384;
                const float* svr = SVb + (size_t)sel * HH;
                for (int idx = t - FF; idx < 512; idx += 256 - FF)
                    rowS[idx] = (idx < 384) ? gir[idx] : svr[idx - 384];
            }
        }
        __syncthreads();

        // ---- P9: wave-parallel rescan of changed features ----
        if (i < SEQ - 1) {
            const int w = t >> 6, lane = t & 63;
            const int n = chgN;
            for (int e = w; e < n; e += 4) {
                int f = chgF[e];
                float om = mxS[f];
                const float* bp = brB + f;
                float v1 = maskS[lane]      ? bp[lane * FF]        : -__builtin_huge_valf();
                float v2 = maskS[lane + 64] ? bp[(lane + 64) * FF] : -__builtin_huge_valf();
                float v; int idx;
                if (v2 > v1) { v = v2; idx = lane + 64; } else { v = v1; idx = lane; }
                for (int off = 32; off >= 1; off >>= 1) {
                    float ov = __shfl_down(v, off);
                    int   oi = __shfl_down(idx, off);
                    if (ov > v || (ov == v && oi < idx)) { v = ov; idx = oi; }
                }
                if (lane == 0) { mxS[f] = v; mxiS[f] = idx; chgDl[e] = v - om; }
            }
        }
        __syncthreads();

        // ---- G: gh partials = h @ WhhT (k-split2, 3 gates) ----
        if (i < SEQ - 1) {
            const float* Wr = WhhT + (size_t)(kh * 64) * 384;
            float ar = 0.f, az = 0.f, an = 0.f;
            for (int m = 0; m < 64; m++) {
                float hv = hS[kh * 64 + m];
                const float* row = Wr + m * 384;
                ar += hv * row[j]; az += hv * row[HH + j]; an += hv * row[2 * HH + j];
            }
            ppG[kh][j] = ar; ppG[2 + kh][j] = az; ppG[4 + kh][j] = an;
        }
        __syncthreads();

        // ---- P10: GRU finish + incremental mxv/sv + next a1 ----
        if (i < SEQ - 1 && t < HH) {
            float ghr = ppG[0][t] + ppG[1][t] + gbhh[t];
            float ghz = ppG[2][t] + ppG[3][t] + gbhh[HH + t];
            float ghn = ppG[4][t] + ppG[5][t] + gbhh[2 * HH + t];
            float rr = 1.f / (1.f + expf(-(rowS[t] + ghr)));
            float zz = 1.f / (1.f + expf(-(rowS[HH + t] + ghz)));
            float nn = tanhf(rowS[2 * HH + t] + rr * ghn);
            hS[t] = (1.f - zz) * nn + zz * hS[t];

            double acc = mxvS[t];
            const int n = chgN;
            for (int e = 0; e < n; e++)
                acc += (double)chgDl[e] * (double)cntW1[chgF[e] * HH + t];
            mxvS[t] = acc;
            double sv = svS[t] - (double)rowS[384 + t];
            svS[t] = sv;
            a1S[t] = fmaxf((float)(acc + sv / (double)(SEQ - 1 - i)) + cntb1[t], 0.f);
        }
        __syncthreads();
    }
}

extern "C" void kernel_launch(void* const* d_in, const int* in_sizes, int n_in,
                              void* d_out, int out_size, void* d_ws, size_t ws_size,
                              hipStream_t stream) {
    (void)in_sizes; (void)n_in; (void)out_size; (void)ws_size;
    const float* br    = (const float*)d_in[0];
    const float* fnnW1 = (const float*)d_in[2];
    const float* fnnb1 = (const float*)d_in[3];
    const float* fnnW2 = (const float*)d_in[4];
    const float* fnnb2 = (const float*)d_in[5];
    const float* cntW1 = (const float*)d_in[6];
    const float* cntb1 = (const float*)d_in[7];
    const float* cntW2 = (const float*)d_in[8];
    const float* cntb2 = (const float*)d_in[9];
    const float* comW1 = (const float*)d_in[10];
    const float* comb1 = (const float*)d_in[11];
    const float* comW2 = (const float*)d_in[12];
    const float* Wih   = (const float*)d_in[14];
    const float* Whh   = (const float*)d_in[15];
    const float* bih   = (const float*)d_in[16];
    const float* bhh   = (const float*)d_in[17];

    float* ws   = (float*)d_ws;
    float* V    = ws;                          // 512*128*128 =  8,388,608 f
    float* GI   = V + 8388608;                 // 512*128*384 = 25,165,824 f
    float* SV   = GI + 25165824;               // 512*128*128 =  8,388,608 f
    float* WihT = SV + 8388608;                // 128*384
    float* WhhT = WihT + 49152;                // 128*384
    // total ws ≈ 168.2 MB

    hipLaunchKernelGGL(k_transpose384, dim3(192), dim3(256), 0, stream, Wih, WihT);
    hipLaunchKernelGGL(k_transpose384, dim3(192), dim3(256), 0, stream, Whh, WhhT);
    hipLaunchKernelGGL(k_docvgi, dim3(2048), dim3(256), 0, stream,
                       br, fnnW1, fnnb1, fnnW2, fnnb2, comW1, WihT, bih, cntW1,
                       V, GI, SV);
    hipLaunchKernelGGL(k_scan4, dim3(BSZ), dim3(256), 0, stream,
                       br, cntW1, cntb1, cntW2, cntb2, comW1, comb1, comW2,
                       WhhT, bhh, V, GI, SV, (float*)d_out);
}

// Round 5
// 9515.684 us; speedup vs baseline: 1.4221x; 1.0324x over previous
//
#include <hip/hip_runtime.h>
#include <math.h>

#define BSZ 512
#define SEQ 128
#define FF  136
#define HH  128

// ---------------- transpose (384x128 -> 128x384) ----------------
__global__ __launch_bounds__(256) void k_transpose384(const float* __restrict__ A,
                                                      float* __restrict__ At) {
    int i = blockIdx.x * 256 + threadIdx.x;          // over 384*128
    if (i < 384 * 128) {
        int r = i >> 7, c = i & 127;
        At[c * 384 + r] = A[i];
    }
}

// ---------------- fused doc FNN + V + GI + SV precompute ----------------
__global__ __launch_bounds__(256) void k_docvgi(
    const float* __restrict__ br,
    const float* __restrict__ fW1, const float* __restrict__ fb1,
    const float* __restrict__ fW2, const float* __restrict__ fb2,
    const float* __restrict__ comW1,
    const float* __restrict__ WihT, const float* __restrict__ bih,
    const float* __restrict__ cntW1,
    float* __restrict__ V, float* __restrict__ GI, float* __restrict__ SV)
{
    __shared__ float xs[32][FF];
    __shared__ float hs[32][HH];
    __shared__ float ds[32][HH];
    int row0 = blockIdx.x * 32;
    int t = threadIdx.x;
    const float* src = br + (size_t)row0 * FF;
    for (int i = t; i < 32 * FF; i += 256) xs[i / FF][i % FF] = src[i];
    __syncthreads();
    int j = t & 127, rg = t >> 7;
    float acc[16];
#pragma unroll
    for (int r = 0; r < 16; r++) acc[r] = 0.f;
    for (int k = 0; k < FF; k++) {
        float w = fW1[k * HH + j];
#pragma unroll
        for (int r = 0; r < 16; r++) acc[r] += xs[rg + 2 * r][k] * w;
    }
    {
        float bb = fb1[j];
#pragma unroll
        for (int r = 0; r < 16; r++) hs[rg + 2 * r][j] = fmaxf(acc[r] + bb, 0.f);
    }
    __syncthreads();
#pragma unroll
    for (int r = 0; r < 16; r++) acc[r] = 0.f;
    for (int k = 0; k < HH; k++) {
        float w = fW2[k * HH + j];
#pragma unroll
        for (int r = 0; r < 16; r++) acc[r] += hs[rg + 2 * r][k] * w;
    }
    {
        float bb = fb2[j];
#pragma unroll
        for (int r = 0; r < 16; r++)
            ds[rg + 2 * r][j] = 1.f / (1.f + expf(-(acc[r] + bb)));
    }
    __syncthreads();
#pragma unroll
    for (int r = 0; r < 16; r++) acc[r] = 0.f;
    for (int k = 0; k < HH; k++) {
        float w = comW1[k * HH + j];
#pragma unroll
        for (int r = 0; r < 16; r++) acc[r] += ds[rg + 2 * r][k] * w;
    }
#pragma unroll
    for (int r = 0; r < 16; r++) V[(size_t)(row0 + rg + 2 * r) * HH + j] = acc[r];
    for (int p = 0; p < 3; p++) {
        int jj = p * HH + j;
#pragma unroll
        for (int r = 0; r < 16; r++) acc[r] = 0.f;
        for (int k = 0; k < HH; k++) {
            float w = WihT[k * 384 + jj];
#pragma unroll
            for (int r = 0; r < 16; r++) acc[r] += ds[rg + 2 * r][k] * w;
        }
        float bb = bih[jj];
#pragma unroll
        for (int r = 0; r < 16; r++)
            GI[(size_t)(row0 + rg + 2 * r) * 384 + jj] = acc[r] + bb;
    }
    // SV = br @ cntW1[FF:2FF,:]
#pragma unroll
    for (int r = 0; r < 16; r++) acc[r] = 0.f;
    for (int k = 0; k < FF; k++) {
        float w = cntW1[(FF + k) * HH + j];
#pragma unroll
        for (int r = 0; r < 16; r++) acc[r] += xs[rg + 2 * r][k] * w;
    }
#pragma unroll
    for (int r = 0; r < 16; r++) SV[(size_t)(row0 + rg + 2 * r) * HH + j] = acc[r];
}

// ---------------- scan: 1 elem/block, 256 threads, r1 footprint, A-phase-free ----------------
__global__ __launch_bounds__(256, 3) void k_scan5(
    const float* __restrict__ br,
    const float* __restrict__ cntW1, const float* __restrict__ cntb1,
    const float* __restrict__ cntW2, const float* __restrict__ cntb2,
    const float* __restrict__ comW1, const float* __restrict__ comb1,
    const float* __restrict__ comW2,
    const float* __restrict__ WhhT, const float* __restrict__ gbhh,
    const float* __restrict__ V, const float* __restrict__ GI,
    const float* __restrict__ SV,
    float* __restrict__ out)
{
    __shared__ float  Vl[SEQ][HH + 1];      // 66 KB, padded -> conflict-free D reads
    __shared__ float  a1S[HH], crS[HH], uS[HH], hS[HH], c2S[HH];
    __shared__ float  pp2[2][HH];           // shared partials for B, C, D (disjoint lifetimes)
    __shared__ float  ppG[6][HH];           // GRU gate partials
    __shared__ float  mxS[FF], chgDl[FF];   // chgDl holds colsum at init
    __shared__ int    mxiS[FF], chgF[FF], maskS[SEQ];
    __shared__ int    selS, chgN;
    // total LDS ~75.4 KB -> 2 blocks/CU

    const int b = blockIdx.x;
    const int t = threadIdx.x;
    const int kh = t >> 7, j = t & 127;
    const float* brB = br + (size_t)b * SEQ * FF;
    const float* GIb = GI + (size_t)b * SEQ * 384;
    const float* SVb = SV + (size_t)b * SEQ * HH;

    // ---- init ----
    {
        const float* Vb = V + (size_t)b * SEQ * HH;
        for (int idx = t; idx < SEQ * HH; idx += 256)
            Vl[idx >> 7][idx & 127] = Vb[idx];
    }
    if (t < HH)  { hS[t] = 0.f; c2S[t] = comW2[t]; }
    if (t < SEQ) maskS[t] = 1;
    if (t < FF) {
        float cs = 0.f; float mx = -__builtin_huge_valf(); int mi = 0;
        const float* bp = brB + t;
        for (int s = 0; s < SEQ; s++) {
            float v = bp[s * FF];
            cs += v;
            if (v > mx) { mx = v; mi = s; }
        }
        mxS[t] = mx; mxiS[t] = mi; chgDl[t] = cs;
    }
    __syncthreads();

    double mxv = 0.0, sv = 0.0;             // per-thread (t<128) fp64 accumulators
    if (t < HH) {
        for (int f = 0; f < FF; f++) {
            mxv += (double)mxS[f]   * (double)cntW1[f * HH + t];
            sv  += (double)chgDl[f] * (double)cntW1[(FF + f) * HH + t];
        }
        a1S[t] = fmaxf((float)(mxv + sv / 128.0) + cntb1[t], 0.f);
    }
    __syncthreads();

    for (int i = 0; i < SEQ; i++) {
        // ---- B: pp2 = a1 @ cntW2 (k-split2) ----
        {
            const float* W = cntW2 + (size_t)(kh * 64) * HH + j;
            const float* a = a1S + kh * 64;
            float acc = 0.f;
            for (int m = 0; m < 64; m++) acc += a[m] * W[m * HH];
            pp2[kh][j] = acc;
        }
        __syncthreads();

        // ---- cr = sigmoid(.) ; reset chg counter ----
        if (t < HH) crS[t] = 1.f / (1.f + expf(-(pp2[0][t] + pp2[1][t] + cntb2[t])));
        else if (t == HH) chgN = 0;
        __syncthreads();

        // ---- C: u-halves: cr @ comW1[128:256] (kh=0) | h @ comW1[256:384] (kh=1) ----
        {
            const float* W = comW1 + (size_t)(HH + kh * HH) * HH + j;
            const float* s0 = kh ? hS : crS;
            float acc = 0.f;
            for (int m = 0; m < 128; m++) acc += s0[m] * W[m * HH];
            pp2[kh][j] = acc;
        }
        __syncthreads();
        if (t < HH) uS[t] = pp2[0][t] + pp2[1][t] + comb1[t];
        __syncthreads();

        // ---- D: score partials (k-split2, LDS only) ----
        {
            float acc = 0.f;
            const int k0 = kh * 64;
            for (int m = 0; m < 64; m++) {
                int k = k0 + m;
                acc += c2S[k] * fmaxf(Vl[j][k] + uS[k], 0.f);
            }
            pp2[kh][j] = acc;
        }
        __syncthreads();

        // ---- argmax (wave 0), first-index tie break ----
        if (t < 64) {
            float s1 = pp2[0][t] + pp2[1][t];
            float s2 = pp2[0][t + 64] + pp2[1][t + 64];
            float v1 = maskS[t]      ? s1 : -__builtin_huge_valf();
            float v2 = maskS[t + 64] ? s2 : -__builtin_huge_valf();
            float v; int idx;
            if (v2 > v1) { v = v2; idx = t + 64; } else { v = v1; idx = t; }
            for (int off = 32; off >= 1; off >>= 1) {
                float ov = __shfl_down(v, off);
                int   oi = __shfl_down(idx, off);
                if (ov > v || (ov == v && oi < idx)) { v = ov; idx = oi; }
            }
            if (t == 0) {
                selS = idx;
                maskS[idx] = 0;
                out[(size_t)b * SEQ + idx] = powf(0.9f, (float)i);
            }
        }
        __syncthreads();
        const int sel = selS;

        float gr0 = 0.f, gr1 = 0.f, gr2 = 0.f, svp = 0.f;  // GI/SV row prefetch regs

        // ---- P8: stale-max detect (t<136) + GI/SV row prefetch (t<128) ----
        if (i < SEQ - 1) {
            if (t < FF && sel == mxiS[t]) {
                int e = atomicAdd(&chgN, 1);
                chgF[e] = t;
            }
            if (t < HH) {
                const float* gir = GIb + (size_t)sel * 384;
                gr0 = gir[t]; gr1 = gir[HH + t]; gr2 = gir[2 * HH + t];
                svp = SVb[(size_t)sel * HH + t];
            }
        }
        __syncthreads();

        // ---- P9: wave-parallel rescan of changed features ----
        if (i < SEQ - 1) {
            const int w = t >> 6, lane = t & 63;
            const int n = chgN;
            for (int e = w; e < n; e += 4) {
                int f = chgF[e];
                float om = mxS[f];
                const float* bp = brB + f;
                float v1 = maskS[lane]      ? bp[lane * FF]        : -__builtin_huge_valf();
                float v2 = maskS[lane + 64] ? bp[(lane + 64) * FF] : -__builtin_huge_valf();
                float v; int idx;
                if (v2 > v1) { v = v2; idx = lane + 64; } else { v = v1; idx = lane; }
                for (int off = 32; off >= 1; off >>= 1) {
                    float ov = __shfl_down(v, off);
                    int   oi = __shfl_down(idx, off);
                    if (ov > v || (ov == v && oi < idx)) { v = ov; idx = oi; }
                }
                if (lane == 0) { mxS[f] = v; mxiS[f] = idx; chgDl[e] = v - om; }
            }
        }
        __syncthreads();

        // ---- G: gh partials = h @ WhhT (k-split2, 3 gates) ----
        if (i < SEQ - 1) {
            const float* Wr = WhhT + (size_t)(kh * 64) * 384;
            float ar = 0.f, az = 0.f, an = 0.f;
            for (int m = 0; m < 64; m++) {
                float hv = hS[kh * 64 + m];
                const float* row = Wr + m * 384;
                ar += hv * row[j]; az += hv * row[HH + j]; an += hv * row[2 * HH + j];
            }
            ppG[kh][j] = ar; ppG[2 + kh][j] = az; ppG[4 + kh][j] = an;
        }
        __syncthreads();

        // ---- P10: GRU finish + incremental mxv/sv + next a1 ----
        if (i < SEQ - 1 && t < HH) {
            float ghr = ppG[0][t] + ppG[1][t] + gbhh[t];
            float ghz = ppG[2][t] + ppG[3][t] + gbhh[HH + t];
            float ghn = ppG[4][t] + ppG[5][t] + gbhh[2 * HH + t];
            float rr = 1.f / (1.f + expf(-(gr0 + ghr)));
            float zz = 1.f / (1.f + expf(-(gr1 + ghz)));
            float nn = tanhf(gr2 + rr * ghn);
            hS[t] = (1.f - zz) * nn + zz * hS[t];

            const int n = chgN;
            for (int e = 0; e < n; e++)
                mxv += (double)chgDl[e] * (double)cntW1[chgF[e] * HH + t];
            sv -= (double)svp;
            a1S[t] = fmaxf((float)(mxv + sv / (double)(SEQ - 1 - i)) + cntb1[t], 0.f);
        }
        __syncthreads();
    }
}

extern "C" void kernel_launch(void* const* d_in, const int* in_sizes, int n_in,
                              void* d_out, int out_size, void* d_ws, size_t ws_size,
                              hipStream_t stream) {
    (void)in_sizes; (void)n_in; (void)out_size; (void)ws_size;
    const float* br    = (const float*)d_in[0];
    const float* fnnW1 = (const float*)d_in[2];
    const float* fnnb1 = (const float*)d_in[3];
    const float* fnnW2 = (const float*)d_in[4];
    const float* fnnb2 = (const float*)d_in[5];
    const float* cntW1 = (const float*)d_in[6];
    const float* cntb1 = (const float*)d_in[7];
    const float* cntW2 = (const float*)d_in[8];
    const float* cntb2 = (const float*)d_in[9];
    const float* comW1 = (const float*)d_in[10];
    const float* comb1 = (const float*)d_in[11];
    const float* comW2 = (const float*)d_in[12];
    const float* Wih   = (const float*)d_in[14];
    const float* Whh   = (const float*)d_in[15];
    const float* bih   = (const float*)d_in[16];
    const float* bhh   = (const float*)d_in[17];

    float* ws   = (float*)d_ws;
    float* V    = ws;                          // 512*128*128 =  8,388,608 f
    float* GI   = V + 8388608;                 // 512*128*384 = 25,165,824 f
    float* SV   = GI + 25165824;               // 512*128*128 =  8,388,608 f
    float* WihT = SV + 8388608;                // 128*384
    float* WhhT = WihT + 49152;                // 128*384

    hipLaunchKernelGGL(k_transpose384, dim3(192), dim3(256), 0, stream, Wih, WihT);
    hipLaunchKernelGGL(k_transpose384, dim3(192), dim3(256), 0, stream, Whh, WhhT);
    hipLaunchKernelGGL(k_docvgi, dim3(2048), dim3(256), 0, stream,
                       br, fnnW1, fnnb1, fnnW2, fnnb2, comW1, WihT, bih, cntW1,
                       V, GI, SV);
    hipLaunchKernelGGL(k_scan5, dim3(BSZ), dim3(256), 0, stream,
                       br, cntW1, cntb1, cntW2, cntb2, comW1, comb1, comW2,
                       WhhT, bhh, V, GI, SV, (float*)d_out);
}